// Round 3
// baseline (392.164 us; speedup 1.0000x reference)
//
#include <hip/hip_runtime.h>
#include <math.h>

#define NN 100000
#define NE 1600000
#define NG (NE / 4)          // 400000 int4 groups, exact

// ---------- P1: degree histogram via global no-return atomics ----------
__global__ void __launch_bounds__(256) deg_kernel(
        const int* __restrict__ col, unsigned* __restrict__ deg) {
    int g = blockIdx.x * 256 + threadIdx.x;
    if (g >= NG) return;
    int4 c4 = ((const int4*)col)[g];
    atomicAdd(&deg[c4.x], 1u);
    atomicAdd(&deg[c4.y], 1u);
    atomicAdd(&deg[c4.z], 1u);
    atomicAdd(&deg[c4.w], 1u);
}

// ---------- P2: conv1 aggregation — gather x/deg, scatter-add msg ----------
__global__ void __launch_bounds__(256) conv1_agg_kernel(
        const int* __restrict__ row, const int* __restrict__ col,
        const float2* __restrict__ x2, const unsigned* __restrict__ deg,
        float2* __restrict__ agg1) {
    int g = blockIdx.x * 256 + threadIdx.x;
    if (g >= NG) return;
    int4 r4 = ((const int4*)row)[g];
    int4 c4 = ((const int4*)col)[g];
    int rr[4] = {r4.x, r4.y, r4.z, r4.w};
    int cc[4] = {c4.x, c4.y, c4.z, c4.w};
    float2 xv[4]; unsigned dg[4];
#pragma unroll
    for (int j = 0; j < 4; ++j) {            // issue all gathers first (ILP)
        xv[j] = x2[rr[j]];
        dg[j] = deg[rr[j]];
    }
#pragma unroll
    for (int j = 0; j < 4; ++j) {
        float dv = dg[j] ? rsqrtf((float)dg[j]) : 0.0f;   // y2 on the fly
        atomicAdd(&agg1[cc[j]].x, xv[j].x * dv);
        atomicAdd(&agg1[cc[j]].y, xv[j].y * dv);
    }
}

// ---------- P2.5: per-node fused MLP (64 hidden, relu) -> z2 ----------
__global__ void __launch_bounds__(256) mlp_kernel(
        const float2* __restrict__ agg1, const unsigned* __restrict__ deg,
        const float* __restrict__ W1, const float* __restrict__ b1,
        const float* __restrict__ W2, float* __restrict__ z2) {
    __shared__ float sW0[64], sW1[64], sb1[64], sW2[64];
    int t = threadIdx.x;
    if (t < 64) { sW0[t] = W1[t]; sW1[t] = W1[64 + t]; sb1[t] = b1[t]; sW2[t] = W2[t]; }
    __syncthreads();
    int n = blockIdx.x * 256 + t;
    if (n >= NN) return;
    unsigned d = deg[n];
    float dv = d ? rsqrtf((float)d) : 0.0f;
    float2 a = agg1[n];
    float a0 = a.x * dv, a1 = a.y * dv;      // dis[col] * sum
    float acc = 0.0f;
#pragma unroll
    for (int j = 0; j < 64; ++j) {
        float h = fmaf(a0, sW0[j], fmaf(a1, sW1[j], sb1[j]));
        acc = fmaf(fmaxf(h, 0.0f), sW2[j], acc);
    }
    z2[n] = acc * dv;                        // pre-multiply dis[row] for layer 2
}

// ---------- P3: conv2 aggregation — gather z2, scatter-add ----------
__global__ void __launch_bounds__(256) conv2_agg_kernel(
        const int* __restrict__ row, const int* __restrict__ col,
        const float* __restrict__ z2, float* __restrict__ agg2) {
    int g = blockIdx.x * 256 + threadIdx.x;
    if (g >= NG) return;
    int4 r4 = ((const int4*)row)[g];
    int4 c4 = ((const int4*)col)[g];
    float zv[4] = {z2[r4.x], z2[r4.y], z2[r4.z], z2[r4.w]};
    atomicAdd(&agg2[c4.x], zv[0]);
    atomicAdd(&agg2[c4.y], zv[1]);
    atomicAdd(&agg2[c4.z], zv[2]);
    atomicAdd(&agg2[c4.w], zv[3]);
}

// ---------- P3.5: bias + relu epilogue ----------
__global__ void __launch_bounds__(256) out_kernel(
        const float* __restrict__ agg2, const unsigned* __restrict__ deg,
        const float* __restrict__ b2, float* __restrict__ out) {
    int n = blockIdx.x * 256 + threadIdx.x;
    if (n >= NN) return;
    unsigned d = deg[n];
    float dv = d ? rsqrtf((float)d) : 0.0f;
    out[n] = fmaxf(fmaf(dv, agg2[n], b2[0]), 0.0f);
}

// ---------- launch ----------
extern "C" void kernel_launch(void* const* d_in, const int* in_sizes, int n_in,
                              void* d_out, int out_size, void* d_ws, size_t ws_size,
                              hipStream_t stream) {
    const float* x  = (const float*)d_in[0];
    const int*   ei = (const int*)d_in[1];     // [2, E] int32: row then col
    const float* W1 = (const float*)d_in[2];
    const float* b1 = (const float*)d_in[3];
    const float* W2 = (const float*)d_in[4];
    const float* b2 = (const float*)d_in[5];
    float* out = (float*)d_out;

    const int* row = ei;
    const int* col = ei + NE;

    // workspace layout (contiguous zero region first: deg, agg1, agg2)
    unsigned* deg  = (unsigned*)d_ws;                    // NN u32
    float2*   agg1 = (float2*)(deg + NN);                // NN float2 (8B-aligned: NN*4 % 16 == 0)
    float*    agg2 = (float*)(agg1 + NN);                // NN f32
    float*    z2   = agg2 + NN;                          // NN f32 (no zeroing needed)

    hipMemsetAsync(deg, 0, (size_t)NN * (4 + 8 + 4), stream);

    const int gE = (NG + 255) / 256;   // 1563
    const int gN = (NN + 255) / 256;   // 391
    deg_kernel      <<<gE, 256, 0, stream>>>(col, deg);
    conv1_agg_kernel<<<gE, 256, 0, stream>>>(row, col, (const float2*)x, deg, agg1);
    mlp_kernel      <<<gN, 256, 0, stream>>>(agg1, deg, W1, b1, W2, z2);
    conv2_agg_kernel<<<gE, 256, 0, stream>>>(row, col, z2, agg2);
    out_kernel      <<<gN, 256, 0, stream>>>(agg2, deg, b2, out);
}

// Round 4
// 282.287 us; speedup vs baseline: 1.3892x; 1.3892x over previous
//
#include <hip/hip_runtime.h>
#include <hip/hip_cooperative_groups.h>
#include <math.h>

namespace cg = cooperative_groups;

#define NN 100000
#define NE 1600000
#define BKT 448            // nodes per bucket (9-bit local index)
#define NB 224             // ceil(100000/448)
#define EPB 6400           // edges per reorder chunk; 250*6400 = 1,600,000 exact
#define NPB 250
#define STRIDE 8192        // slots per bucket (mean 7168, sd ~85 -> +12 sigma)
#define RT 1024

// ---------- K1: reorder edges into fixed-stride bucket runs (verified R1) ----------
// packed record = (row << 9) | cl, cl = col - bucket*448 (< 448 < 512)
__global__ void __launch_bounds__(RT) reorder_kernel(
        const int* __restrict__ row, const int* __restrict__ col,
        unsigned* __restrict__ cursor, unsigned* __restrict__ packed) {
    __shared__ int h[NB], lb[NB];
    __shared__ unsigned gaddr[NB], glim[NB];
    __shared__ int wsum[RT / 64];
    __shared__ uint2 sga[EPB];                 // (record, final global slot) — 50 KB
    const int t = threadIdx.x;
    const int lane = t & 63, wid = t >> 6;
    const int e0 = blockIdx.x * EPB;

    for (int i = t; i < NB; i += RT) h[i] = 0;
    __syncthreads();

    const int4* rv = (const int4*)(row + e0);
    const int4* cv = (const int4*)(col + e0);
    unsigned pk[8]; int bb[8];
#pragma unroll
    for (int u = 0; u < 8; ++u) bb[u] = -1;
#pragma unroll
    for (int g = 0; g < 2; ++g) {
        int grp = g * RT + t;
        if (grp < EPB / 4) {
            int4 r4 = rv[grp], c4 = cv[grp];
            int rr[4] = {r4.x, r4.y, r4.z, r4.w};
            int cc[4] = {c4.x, c4.y, c4.z, c4.w};
#pragma unroll
            for (int j = 0; j < 4; ++j) {
                int b = cc[j] / BKT;            // compiler magic-mul
                int cl = cc[j] - b * BKT;
                pk[4 * g + j] = ((unsigned)rr[j] << 9) | (unsigned)cl;
                bb[4 * g + j] = b;
            }
        }
    }
#pragma unroll
    for (int u = 0; u < 8; ++u)
        if (bb[u] >= 0) atomicAdd(&h[bb[u]], 1);
    __syncthreads();

    int v = (t < NB) ? h[t] : 0;
    int incl = v;
#pragma unroll
    for (int d = 1; d < 64; d <<= 1) {
        int u2 = __shfl_up(incl, d);
        if (lane >= d) incl += u2;
    }
    if (lane == 63) wsum[wid] = incl;
    __syncthreads();
    int off = 0;
#pragma unroll
    for (int j = 0; j < 3; ++j)
        if (j < wid) off += wsum[j];
    if (t < NB) {
        lb[t] = off + incl - v;
        unsigned base = v ? atomicAdd(&cursor[t], (unsigned)v) : 0u;
        gaddr[t] = (unsigned)t * STRIDE + base;
        glim[t]  = (unsigned)(t + 1) * STRIDE;
    }
    __syncthreads();
    for (int i = t; i < NB; i += RT) h[i] = 0;  // reuse as rank counters
    __syncthreads();

#pragma unroll
    for (int u = 0; u < 8; ++u) {
        if (bb[u] >= 0) {
            int b = bb[u];
            int r = atomicAdd(&h[b], 1);
            unsigned a = gaddr[b] + (unsigned)r;
            if (a >= glim[b]) a = 0xFFFFFFFFu;  // overflow guard (statistically never)
            sga[lb[b] + r] = make_uint2(pk[u], a);
        }
    }
    __syncthreads();
    for (int i = t; i < EPB; i += RT) {
        uint2 e = sga[i];
        if (e.y != 0xFFFFFFFFu) packed[e.y] = e.x;
    }
}

// ---------- K2': cooperative fused sort + conv1 + conv2 ----------
// phase A: histogram -> deg, y2    | gridsync |
// phase B: rank-scatter -> LDS srt; conv1 (gather y2) -> z2   | gridsync |
// phase C: conv2 from LDS srt (gather z2) -> out
__global__ void __launch_bounds__(RT) fused_kernel(
        const unsigned* __restrict__ packed, const unsigned* __restrict__ cursor,
        const float2* __restrict__ x2,
        const float* __restrict__ W1, const float* __restrict__ b1,
        const float* __restrict__ W2, const float* __restrict__ b2,
        float2* __restrict__ y2, float* __restrict__ z2, float* __restrict__ out) {
    __shared__ int cnt[BKT], rk[BKT], sexA[BKT];
    __shared__ int wsum[(BKT + 63) / 64];      // 7
    __shared__ float sW0[64], sW1[64], sb1[64], sW2[64];
    __shared__ unsigned srt[STRIDE];           // 32 KB, persists across grid syncs
    cg::grid_group grid = cg::this_grid();

    const int t = threadIdx.x;
    const int lane = t & 63, wid = t >> 6;
    const int b = blockIdx.x;
    const unsigned s0 = (unsigned)b * STRIDE;
    const int L = min((int)cursor[b], STRIDE);
    const int L4 = L >> 2;

    if (t < 64) { sW0[t] = W1[t]; sW1[t] = W1[64 + t]; sb1[t] = b1[t]; sW2[t] = W2[t]; }
    for (int i = t; i < BKT; i += RT) { cnt[i] = 0; rk[i] = 0; }
    __syncthreads();

    // ---- phase A: histogram (uint4 global reads) ----
    const uint4* pv4 = (const uint4*)(packed + s0);
    for (int g = t; g < L4; g += RT) {
        uint4 p4 = pv4[g];
        atomicAdd(&cnt[p4.x & 511u], 1);
        atomicAdd(&cnt[p4.y & 511u], 1);
        atomicAdd(&cnt[p4.z & 511u], 1);
        atomicAdd(&cnt[p4.w & 511u], 1);
    }
    for (int i = 4 * L4 + t; i < L; i += RT)
        atomicAdd(&cnt[packed[s0 + i] & 511u], 1);
    __syncthreads();

    // ---- exclusive scan over BKT bins ----
    int v = (t < BKT) ? cnt[t] : 0;
    int incl = v;
#pragma unroll
    for (int d = 1; d < 64; d <<= 1) {
        int u2 = __shfl_up(incl, d);
        if (lane >= d) incl += u2;
    }
    if (lane == 63 && wid < (BKT + 63) / 64) wsum[wid] = incl;
    __syncthreads();
    int off = 0;
#pragma unroll
    for (int j = 0; j < (BKT + 63) / 64 - 1; ++j)
        if (j < wid) off += wsum[j];
    if (t < BKT) {
        sexA[t] = off + incl - v;
        int node = b * BKT + t;
        if (node < NN) {
            float dv = (v > 0) ? rsqrtf((float)v) : 0.0f;
            float2 xv = x2[node];
            y2[node] = make_float2(xv.x * dv, xv.y * dv);
        }
    }
    __threadfence();
    grid.sync();                               // y2 + all packed visible

    // ---- phase B: rank-scatter into LDS (packed re-read, L2-hot) ----
    for (int g = t; g < L4; g += RT) {
        uint4 p4 = pv4[g];
        unsigned pp[4] = {p4.x, p4.y, p4.z, p4.w};
#pragma unroll
        for (int j = 0; j < 4; ++j) {
            int cl = pp[j] & 511u;
            int r = atomicAdd(&rk[cl], 1);
            srt[sexA[cl] + r] = pp[j] >> 9;
        }
    }
    for (int i = 4 * L4 + t; i < L; i += RT) {
        unsigned p = packed[s0 + i];
        int cl = p & 511u;
        int r = atomicAdd(&rk[cl], 1);
        srt[sexA[cl] + r] = p >> 9;
    }
    __syncthreads();

    // ---- conv1: 2 threads per node, gather y2, fused MLP ----
    const int tau = t >> 1, par = t & 1;
    if (t < 2 * BKT) {
        int start = sexA[tau], deg = cnt[tau];
        float sx = 0.f, sy = 0.f;
        for (int k = start + par; k < start + deg; k += 2) {
            float2 w = y2[srt[k]];
            sx += w.x; sy += w.y;
        }
        sx += __shfl_xor(sx, 1); sy += __shfl_xor(sy, 1);
        float dv = (deg > 0) ? rsqrtf((float)deg) : 0.0f;
        float a0 = sx * dv, a1 = sy * dv;
        float acc = 0.0f;
        int j0 = par * 32;                     // MLP split across the pair
#pragma unroll
        for (int jj = 0; jj < 32; ++jj) {
            int j = j0 + jj;
            float h = fmaf(a0, sW0[j], fmaf(a1, sW1[j], sb1[j]));
            acc = fmaf(fmaxf(h, 0.0f), sW2[j], acc);
        }
        acc += __shfl_xor(acc, 1);
        int node = b * BKT + tau;
        if (par == 0 && node < NN) z2[node] = acc * dv;  // dis[row] pre-folded
    }
    __threadfence();
    grid.sync();                               // z2 visible

    // ---- phase C: conv2 straight from LDS srt ----
    if (t < 2 * BKT) {
        int start = sexA[tau], deg = cnt[tau];
        float s = 0.f;
        for (int k = start + par; k < start + deg; k += 2)
            s += z2[srt[k]];
        s += __shfl_xor(s, 1);
        int node = b * BKT + tau;
        if (par == 0 && node < NN) {
            float dv = (deg > 0) ? rsqrtf((float)deg) : 0.0f;
            out[node] = fmaxf(fmaf(dv, s, b2[0]), 0.0f);
        }
    }
}

// ---------- launch ----------
extern "C" void kernel_launch(void* const* d_in, const int* in_sizes, int n_in,
                              void* d_out, int out_size, void* d_ws, size_t ws_size,
                              hipStream_t stream) {
    const float* x  = (const float*)d_in[0];
    const int*   ei = (const int*)d_in[1];     // [2, E] int32: row then col
    const float* W1 = (const float*)d_in[2];
    const float* b1 = (const float*)d_in[3];
    const float* W2 = (const float*)d_in[4];
    const float* b2 = (const float*)d_in[5];
    float* out = (float*)d_out;

    const int* row = ei;
    const int* col = ei + NE;

    // workspace layout
    unsigned* packed = (unsigned*)d_ws;                    // NB*STRIDE (~7.3 MB)
    float2*   y2     = (float2*)(packed + (size_t)NB * STRIDE); // NN float2
    float*    z2     = (float*)(y2 + NN);                  // NN
    unsigned* cursor = (unsigned*)(z2 + NN);               // NB

    hipMemsetAsync(cursor, 0, NB * sizeof(unsigned), stream);

    reorder_kernel<<<NPB, RT, 0, stream>>>(row, col, cursor, packed);

    void* args[] = {(void*)&packed, (void*)&cursor, (void*)&x,
                    (void*)&W1, (void*)&b1, (void*)&W2, (void*)&b2,
                    (void*)&y2, (void*)&z2, (void*)&out};
    hipLaunchCooperativeKernel((void*)fused_kernel, dim3(NB), dim3(RT),
                               args, 0, stream);
}

// Round 5
// 111.277 us; speedup vs baseline: 3.5242x; 2.5368x over previous
//
#include <hip/hip_runtime.h>
#include <math.h>

#define NN 100000
#define NE 1600000
#define BKT 448            // nodes per bucket (9-bit local index)
#define NB 224             // ceil(100000/448)
#define EPB 6400           // edges per reorder chunk; 250*6400 = 1,600,000 exact
#define NPB 250
#define STRIDE 8192        // slots per bucket (mean 7168, sd ~85 -> +12 sigma)
#define RT 1024

// ---------- K1: reorder edges into fixed-stride bucket runs (verified R1) ----------
// packed record = (row << 9) | cl, cl = col - bucket*448 (< 448 < 512)
__global__ void __launch_bounds__(RT) reorder_kernel(
        const int* __restrict__ row, const int* __restrict__ col,
        unsigned* __restrict__ cursor, unsigned* __restrict__ packed) {
    __shared__ int h[NB], lb[NB];
    __shared__ unsigned gaddr[NB], glim[NB];
    __shared__ int wsum[RT / 64];
    __shared__ uint2 sga[EPB];                 // (record, final global slot) — 50 KB
    const int t = threadIdx.x;
    const int lane = t & 63, wid = t >> 6;
    const int e0 = blockIdx.x * EPB;

    for (int i = t; i < NB; i += RT) h[i] = 0;
    __syncthreads();

    const int4* rv = (const int4*)(row + e0);
    const int4* cv = (const int4*)(col + e0);
    unsigned pk[8]; int bb[8];
#pragma unroll
    for (int u = 0; u < 8; ++u) bb[u] = -1;
#pragma unroll
    for (int g = 0; g < 2; ++g) {
        int grp = g * RT + t;
        if (grp < EPB / 4) {
            int4 r4 = rv[grp], c4 = cv[grp];
            int rr[4] = {r4.x, r4.y, r4.z, r4.w};
            int cc[4] = {c4.x, c4.y, c4.z, c4.w};
#pragma unroll
            for (int j = 0; j < 4; ++j) {
                int b = cc[j] / BKT;            // compiler magic-mul
                int cl = cc[j] - b * BKT;
                pk[4 * g + j] = ((unsigned)rr[j] << 9) | (unsigned)cl;
                bb[4 * g + j] = b;
            }
        }
    }
#pragma unroll
    for (int u = 0; u < 8; ++u)
        if (bb[u] >= 0) atomicAdd(&h[bb[u]], 1);
    __syncthreads();

    int v = (t < NB) ? h[t] : 0;
    int incl = v;
#pragma unroll
    for (int d = 1; d < 64; d <<= 1) {
        int u2 = __shfl_up(incl, d);
        if (lane >= d) incl += u2;
    }
    if (lane == 63) wsum[wid] = incl;
    __syncthreads();
    int off = 0;
#pragma unroll
    for (int j = 0; j < 3; ++j)
        if (j < wid) off += wsum[j];
    if (t < NB) {
        lb[t] = off + incl - v;
        unsigned base = v ? atomicAdd(&cursor[t], (unsigned)v) : 0u;
        gaddr[t] = (unsigned)t * STRIDE + base;
        glim[t]  = (unsigned)(t + 1) * STRIDE;
    }
    __syncthreads();
    for (int i = t; i < NB; i += RT) h[i] = 0;  // reuse as rank counters
    __syncthreads();

#pragma unroll
    for (int u = 0; u < 8; ++u) {
        if (bb[u] >= 0) {
            int b = bb[u];
            int r = atomicAdd(&h[b], 1);
            unsigned a = gaddr[b] + (unsigned)r;
            if (a >= glim[b]) a = 0xFFFFFFFFu;  // overflow guard (statistically never)
            sga[lb[b] + r] = make_uint2(pk[u], a);
        }
    }
    __syncthreads();
    for (int i = t; i < EPB; i += RT) {
        uint2 e = sga[i];
        if (e.y != 0xFFFFFFFFu) packed[e.y] = e.x;
    }
}

// ---------- K2a: per-bucket degree histogram -> dis + y2 (verified R2) ----------
__global__ void __launch_bounds__(RT) degree_kernel(
        const unsigned* __restrict__ packed, const unsigned* __restrict__ cursor,
        const float2* __restrict__ x2,
        float* __restrict__ dis, float2* __restrict__ y2) {
    __shared__ int cnt[BKT];
    const int t = threadIdx.x;
    const int b = blockIdx.x;
    const unsigned s0 = (unsigned)b * STRIDE;
    const int L = min((int)cursor[b], STRIDE);
    const int L4 = L >> 2;

    for (int i = t; i < BKT; i += RT) cnt[i] = 0;
    __syncthreads();

    const uint4* pv4 = (const uint4*)(packed + s0);
    for (int g = t; g < L4; g += RT) {
        uint4 p4 = pv4[g];
        atomicAdd(&cnt[p4.x & 511u], 1);
        atomicAdd(&cnt[p4.y & 511u], 1);
        atomicAdd(&cnt[p4.z & 511u], 1);
        atomicAdd(&cnt[p4.w & 511u], 1);
    }
    for (int i = 4 * L4 + t; i < L; i += RT)
        atomicAdd(&cnt[packed[s0 + i] & 511u], 1);
    __syncthreads();

    int node = b * BKT + t;
    if (t < BKT && node < NN) {
        int v = cnt[t];
        float dv = (v > 0) ? rsqrtf((float)v) : 0.0f;
        dis[node] = dv;
        float2 xv = x2[node];
        y2[node] = make_float2(xv.x * dv, xv.y * dv);
    }
}

// ---------- K2b: counting sort -> srow/node_rng + fused conv1 from LDS srt ----------
__global__ void __launch_bounds__(RT) sortconv1_kernel(
        const unsigned* __restrict__ packed, const unsigned* __restrict__ cursor,
        const float2* __restrict__ y2,
        const float* __restrict__ W1, const float* __restrict__ b1,
        const float* __restrict__ W2,
        unsigned* __restrict__ srow, int2* __restrict__ node_rng,
        float* __restrict__ z2) {
    __shared__ int cnt[BKT], rk[BKT], sexA[BKT];
    __shared__ int wsum[(BKT + 63) / 64];      // 7
    __shared__ float sW0[64], sW1[64], sb1[64], sW2[64];
    __shared__ unsigned srt[STRIDE];           // 32 KB
    const int t = threadIdx.x;
    const int lane = t & 63, wid = t >> 6;
    const int b = blockIdx.x;
    const unsigned s0 = (unsigned)b * STRIDE;
    const int L = min((int)cursor[b], STRIDE);
    const int L4 = L >> 2;

    if (t < 64) { sW0[t] = W1[t]; sW1[t] = W1[64 + t]; sb1[t] = b1[t]; sW2[t] = W2[t]; }
    for (int i = t; i < BKT; i += RT) { cnt[i] = 0; rk[i] = 0; }
    __syncthreads();

    // ---- pass 1: histogram (uint4 global reads) ----
    const uint4* pv4 = (const uint4*)(packed + s0);
    for (int g = t; g < L4; g += RT) {
        uint4 p4 = pv4[g];
        atomicAdd(&cnt[p4.x & 511u], 1);
        atomicAdd(&cnt[p4.y & 511u], 1);
        atomicAdd(&cnt[p4.z & 511u], 1);
        atomicAdd(&cnt[p4.w & 511u], 1);
    }
    for (int i = 4 * L4 + t; i < L; i += RT)
        atomicAdd(&cnt[packed[s0 + i] & 511u], 1);
    __syncthreads();

    // ---- exclusive scan over BKT bins ----
    int v = (t < BKT) ? cnt[t] : 0;
    int incl = v;
#pragma unroll
    for (int d = 1; d < 64; d <<= 1) {
        int u2 = __shfl_up(incl, d);
        if (lane >= d) incl += u2;
    }
    if (lane == 63 && wid < (BKT + 63) / 64) wsum[wid] = incl;
    __syncthreads();
    int off = 0;
#pragma unroll
    for (int j = 0; j < (BKT + 63) / 64 - 1; ++j)
        if (j < wid) off += wsum[j];
    if (t < BKT) {
        int sex = off + incl - v;
        sexA[t] = sex;
        int node = b * BKT + t;
        if (node < NN)
            node_rng[node] = make_int2((int)(s0 + sex), (int)(s0 + sex + v));
    }
    __syncthreads();

    // ---- pass 2: rank-scatter (re-read L2-hot packed) ----
    for (int g = t; g < L4; g += RT) {
        uint4 p4 = pv4[g];
        unsigned pp[4] = {p4.x, p4.y, p4.z, p4.w};
#pragma unroll
        for (int j = 0; j < 4; ++j) {
            int cl = pp[j] & 511u;
            int r = atomicAdd(&rk[cl], 1);
            srt[sexA[cl] + r] = pp[j] >> 9;
        }
    }
    for (int i = 4 * L4 + t; i < L; i += RT) {
        unsigned p = packed[s0 + i];
        int cl = p & 511u;
        int r = atomicAdd(&rk[cl], 1);
        srt[sexA[cl] + r] = p >> 9;
    }
    __syncthreads();

    // ---- coalesced srow write-out (uint4) — K4 consumes this ----
    uint4* so4 = (uint4*)(srow + s0);
    for (int g = t; g < L4; g += RT) so4[g] = ((const uint4*)srt)[g];
    for (int i = 4 * L4 + t; i < L; i += RT) srow[s0 + i] = srt[i];

    // ---- fused conv1: 2 threads per node from resident srt (verified R4) ----
    const int tau = t >> 1, par = t & 1;
    if (t < 2 * BKT) {
        int start = sexA[tau], deg = cnt[tau];
        float sx = 0.f, sy = 0.f;
        for (int k = start + par; k < start + deg; k += 2) {
            float2 w = y2[srt[k]];
            sx += w.x; sy += w.y;
        }
        sx += __shfl_xor(sx, 1); sy += __shfl_xor(sy, 1);
        float dv = (deg > 0) ? rsqrtf((float)deg) : 0.0f;
        float a0 = sx * dv, a1 = sy * dv;
        float acc = 0.0f;
        int j0 = par * 32;                     // MLP split across the pair
#pragma unroll
        for (int jj = 0; jj < 32; ++jj) {
            int j = j0 + jj;
            float h = fmaf(a0, sW0[j], fmaf(a1, sW1[j], sb1[j]));
            acc = fmaf(fmaxf(h, 0.0f), sW2[j], acc);
        }
        acc += __shfl_xor(acc, 1);
        int node = b * BKT + tau;
        if (par == 0 && node < NN) z2[node] = acc * dv;  // dis[row] pre-folded
    }
}

// ---------- K4: conv2 — 4-lane quad per node, CSR gather + bias + relu (verified R1) ----------
__global__ void conv2_kernel(const unsigned* __restrict__ srow, const int2* __restrict__ node_rng,
                             const float* __restrict__ z2, const float* __restrict__ dis,
                             const float* __restrict__ b2, float* __restrict__ out) {
    int t = threadIdx.x;
    int lane = t & 3;
    int node = blockIdx.x * 64 + (t >> 2);
    if (node >= NN) return;
    int2 rng = node_rng[node];
    float s = 0.f;
    for (int k = rng.x + lane; k < rng.y; k += 4)
        s += z2[srow[k]];
    s += __shfl_xor(s, 1);
    s += __shfl_xor(s, 2);
    if (lane == 0)
        out[node] = fmaxf(fmaf(dis[node], s, b2[0]), 0.0f);
}

// ---------- launch ----------
extern "C" void kernel_launch(void* const* d_in, const int* in_sizes, int n_in,
                              void* d_out, int out_size, void* d_ws, size_t ws_size,
                              hipStream_t stream) {
    const float* x  = (const float*)d_in[0];
    const int*   ei = (const int*)d_in[1];     // [2, E] int32: row then col
    const float* W1 = (const float*)d_in[2];
    const float* b1 = (const float*)d_in[3];
    const float* W2 = (const float*)d_in[4];
    const float* b2 = (const float*)d_in[5];
    float* out = (float*)d_out;

    const int* row = ei;
    const int* col = ei + NE;

    // workspace layout
    unsigned* packed   = (unsigned*)d_ws;              // NB*STRIDE (~7.3 MB)
    unsigned* srow     = packed + (size_t)NB * STRIDE; // NB*STRIDE (~7.3 MB)
    float2*   y2       = (float2*)(srow + (size_t)NB * STRIDE); // NN float2
    float*    dis      = (float*)(y2 + NN);            // NN
    float*    z2       = dis + NN;                     // NN
    int2*     node_rng = (int2*)(z2 + NN);             // NN int2
    unsigned* cursor   = (unsigned*)(node_rng + NN);   // NB

    hipMemsetAsync(cursor, 0, NB * sizeof(unsigned), stream);

    reorder_kernel  <<<NPB, RT, 0, stream>>>(row, col, cursor, packed);
    degree_kernel   <<<NB, RT, 0, stream>>>(packed, cursor, (const float2*)x, dis, y2);
    sortconv1_kernel<<<NB, RT, 0, stream>>>(packed, cursor, (const float2*)y2,
                                            W1, b1, W2, srow, node_rng, z2);
    conv2_kernel    <<<(NN + 63) / 64, 256, 0, stream>>>(srow, node_rng, z2, dis, b2, out);
}

// Round 6
// 110.151 us; speedup vs baseline: 3.5602x; 1.0102x over previous
//
#include <hip/hip_runtime.h>
#include <math.h>

#define NN 100000
#define NE 1600000
#define BKT 391            // nodes per bucket (9-bit local index; 391*256 = 100096)
#define NB 256             // one bucket per CU, full machine
#define EPB 6400           // edges per reorder chunk; 250*6400 = 1,600,000 exact
#define NPB 250
#define STRIDE 7168        // slots per bucket (mean 6256, sd ~79 -> +11.6 sigma)
#define RT 1024

// ---------- K1: reorder edges into fixed-stride bucket runs (verified R1/R5) ----------
// packed record = (row << 9) | cl, cl = col - bucket*BKT (< 391 < 512)
__global__ void __launch_bounds__(RT) reorder_kernel(
        const int* __restrict__ row, const int* __restrict__ col,
        unsigned* __restrict__ cursor, unsigned* __restrict__ packed) {
    __shared__ int h[NB], lb[NB];
    __shared__ unsigned gaddr[NB], glim[NB];
    __shared__ int wsum[RT / 64];
    __shared__ uint2 sga[EPB];                 // (record, final global slot) — 50 KB
    const int t = threadIdx.x;
    const int lane = t & 63, wid = t >> 6;
    const int e0 = blockIdx.x * EPB;

    for (int i = t; i < NB; i += RT) h[i] = 0;
    __syncthreads();

    const int4* rv = (const int4*)(row + e0);
    const int4* cv = (const int4*)(col + e0);
    unsigned pk[8]; int bb[8];
#pragma unroll
    for (int u = 0; u < 8; ++u) bb[u] = -1;
#pragma unroll
    for (int g = 0; g < 2; ++g) {
        int grp = g * RT + t;
        if (grp < EPB / 4) {
            int4 r4 = rv[grp], c4 = cv[grp];
            int rr[4] = {r4.x, r4.y, r4.z, r4.w};
            int cc[4] = {c4.x, c4.y, c4.z, c4.w};
#pragma unroll
            for (int j = 0; j < 4; ++j) {
                int b = cc[j] / BKT;            // compiler magic-mul
                int cl = cc[j] - b * BKT;
                pk[4 * g + j] = ((unsigned)rr[j] << 9) | (unsigned)cl;
                bb[4 * g + j] = b;
            }
        }
    }
#pragma unroll
    for (int u = 0; u < 8; ++u)
        if (bb[u] >= 0) atomicAdd(&h[bb[u]], 1);
    __syncthreads();

    // ---- exclusive scan over NB=256 bins (exactly 4 waves) ----
    int v = (t < NB) ? h[t] : 0;
    int incl = v;
#pragma unroll
    for (int d = 1; d < 64; d <<= 1) {
        int u2 = __shfl_up(incl, d);
        if (lane >= d) incl += u2;
    }
    if (lane == 63) wsum[wid] = incl;
    __syncthreads();
    int off = 0;
#pragma unroll
    for (int j = 0; j < 3; ++j)
        if (j < wid) off += wsum[j];
    if (t < NB) {
        lb[t] = off + incl - v;
        unsigned base = v ? atomicAdd(&cursor[t], (unsigned)v) : 0u;
        gaddr[t] = (unsigned)t * STRIDE + base;
        glim[t]  = (unsigned)(t + 1) * STRIDE;
    }
    __syncthreads();
    for (int i = t; i < NB; i += RT) h[i] = 0;  // reuse as rank counters
    __syncthreads();

#pragma unroll
    for (int u = 0; u < 8; ++u) {
        if (bb[u] >= 0) {
            int b = bb[u];
            int r = atomicAdd(&h[b], 1);
            unsigned a = gaddr[b] + (unsigned)r;
            if (a >= glim[b]) a = 0xFFFFFFFFu;  // overflow guard (statistically never)
            sga[lb[b] + r] = make_uint2(pk[u], a);
        }
    }
    __syncthreads();
    for (int i = t; i < EPB; i += RT) {
        uint2 e = sga[i];
        if (e.y != 0xFFFFFFFFu) packed[e.y] = e.x;
    }
}

// ---------- K2a: histogram + scan -> y2, rng32=(sex<<16|deg) ----------
__global__ void __launch_bounds__(RT) degscan_kernel(
        const unsigned* __restrict__ packed, const unsigned* __restrict__ cursor,
        const float2* __restrict__ x2,
        float2* __restrict__ y2, unsigned* __restrict__ rng32) {
    __shared__ int cnt[BKT];
    __shared__ int wsum[(BKT + 63) / 64];      // 7
    const int t = threadIdx.x;
    const int lane = t & 63, wid = t >> 6;
    const int b = blockIdx.x;
    const unsigned s0 = (unsigned)b * STRIDE;
    const int L = min((int)cursor[b], STRIDE);
    const int L4 = L >> 2;

    for (int i = t; i < BKT; i += RT) cnt[i] = 0;
    __syncthreads();

    const uint4* pv4 = (const uint4*)(packed + s0);
    for (int g = t; g < L4; g += RT) {
        uint4 p4 = pv4[g];
        atomicAdd(&cnt[p4.x & 511u], 1);
        atomicAdd(&cnt[p4.y & 511u], 1);
        atomicAdd(&cnt[p4.z & 511u], 1);
        atomicAdd(&cnt[p4.w & 511u], 1);
    }
    for (int i = 4 * L4 + t; i < L; i += RT)
        atomicAdd(&cnt[packed[s0 + i] & 511u], 1);
    __syncthreads();

    // ---- exclusive scan over BKT bins (7 waves) ----
    int v = (t < BKT) ? cnt[t] : 0;
    int incl = v;
#pragma unroll
    for (int d = 1; d < 64; d <<= 1) {
        int u2 = __shfl_up(incl, d);
        if (lane >= d) incl += u2;
    }
    if (lane == 63 && wid < (BKT + 63) / 64) wsum[wid] = incl;
    __syncthreads();
    int off = 0;
#pragma unroll
    for (int j = 0; j < (BKT + 63) / 64 - 1; ++j)
        if (j < wid) off += wsum[j];
    if (t < BKT) {
        int sex = off + incl - v;              // < STRIDE=7168, fits 16 bits
        int node = b * BKT + t;
        if (node < NN) {
            float dv = (v > 0) ? rsqrtf((float)v) : 0.0f;
            float2 xv = x2[node];
            y2[node] = make_float2(xv.x * dv, xv.y * dv);
            rng32[node] = ((unsigned)sex << 16) | (unsigned)v;   // deg < 65536
        }
    }
}

// ---------- K2b: rank-scatter (using precomputed scan) + srow + fused conv1 ----------
__global__ void __launch_bounds__(RT) sortconv1_kernel(
        const unsigned* __restrict__ packed, const unsigned* __restrict__ cursor,
        const float2* __restrict__ y2, const unsigned* __restrict__ rng32,
        const float* __restrict__ W1, const float* __restrict__ b1,
        const float* __restrict__ W2,
        unsigned* __restrict__ srow, float* __restrict__ z2) {
    __shared__ int rk[BKT], sexA[BKT], cntA[BKT];
    __shared__ float sW0[64], sW1[64], sb1[64], sW2[64];
    __shared__ unsigned srt[STRIDE];           // 28 KB
    const int t = threadIdx.x;
    const int b = blockIdx.x;
    const unsigned s0 = (unsigned)b * STRIDE;
    const int L = min((int)cursor[b], STRIDE);
    const int L4 = L >> 2;

    if (t < 64) { sW0[t] = W1[t]; sW1[t] = W1[64 + t]; sb1[t] = b1[t]; sW2[t] = W2[t]; }
    for (int i = t; i < BKT; i += RT) rk[i] = 0;
    if (t < BKT) {
        int node = b * BKT + t;
        unsigned u = (node < NN) ? rng32[node] : 0u;
        sexA[t] = (int)(u >> 16);
        cntA[t] = (int)(u & 0xFFFFu);
    }
    __syncthreads();

    // ---- rank-scatter (packed read once; hist/scan reused from K2a) ----
    const uint4* pv4 = (const uint4*)(packed + s0);
    for (int g = t; g < L4; g += RT) {
        uint4 p4 = pv4[g];
        unsigned pp[4] = {p4.x, p4.y, p4.z, p4.w};
#pragma unroll
        for (int j = 0; j < 4; ++j) {
            int cl = pp[j] & 511u;
            int r = atomicAdd(&rk[cl], 1);
            srt[sexA[cl] + r] = pp[j] >> 9;
        }
    }
    for (int i = 4 * L4 + t; i < L; i += RT) {
        unsigned p = packed[s0 + i];
        int cl = p & 511u;
        int r = atomicAdd(&rk[cl], 1);
        srt[sexA[cl] + r] = p >> 9;
    }
    __syncthreads();

    // ---- coalesced srow write-out (uint4) — conv2 consumes this ----
    uint4* so4 = (uint4*)(srow + s0);
    for (int g = t; g < L4; g += RT) so4[g] = ((const uint4*)srt)[g];
    for (int i = 4 * L4 + t; i < L; i += RT) srow[s0 + i] = srt[i];

    // ---- fused conv1: 2 threads per node from resident srt (verified R5) ----
    const int tau = t >> 1, par = t & 1;
    if (t < 2 * BKT) {
        int start = sexA[tau], deg = cntA[tau];
        float sx = 0.f, sy = 0.f;
        for (int k = start + par; k < start + deg; k += 2) {
            float2 w = y2[srt[k]];
            sx += w.x; sy += w.y;
        }
        sx += __shfl_xor(sx, 1); sy += __shfl_xor(sy, 1);
        float dv = (deg > 0) ? rsqrtf((float)deg) : 0.0f;
        float a0 = sx * dv, a1 = sy * dv;
        float acc = 0.0f;
        int j0 = par * 32;                     // MLP split across the pair
#pragma unroll
        for (int jj = 0; jj < 32; ++jj) {
            int j = j0 + jj;
            float h = fmaf(a0, sW0[j], fmaf(a1, sW1[j], sb1[j]));
            acc = fmaf(fmaxf(h, 0.0f), sW2[j], acc);
        }
        acc += __shfl_xor(acc, 1);
        int node = b * BKT + tau;
        if (par == 0 && node < NN) z2[node] = acc * dv;  // dis[row] pre-folded
    }
}

// ---------- K4: conv2 — 4-lane quad per node, rng32-driven CSR gather ----------
__global__ void conv2_kernel(const unsigned* __restrict__ srow, const unsigned* __restrict__ rng32,
                             const float* __restrict__ z2,
                             const float* __restrict__ b2, float* __restrict__ out) {
    int t = threadIdx.x;
    int lane = t & 3;
    int node = blockIdx.x * 64 + (t >> 2);
    if (node >= NN) return;
    unsigned u = rng32[node];
    int bk = node / BKT;                       // compiler magic-mul
    unsigned start = (unsigned)bk * STRIDE + (u >> 16);
    int deg = (int)(u & 0xFFFFu);
    float s = 0.f;
    for (unsigned k = start + lane; k < start + (unsigned)deg; k += 4)
        s += z2[srow[k]];
    s += __shfl_xor(s, 1);
    s += __shfl_xor(s, 2);
    if (lane == 0) {
        float dv = (deg > 0) ? rsqrtf((float)deg) : 0.0f;
        out[node] = fmaxf(fmaf(dv, s, b2[0]), 0.0f);
    }
}

// ---------- launch ----------
extern "C" void kernel_launch(void* const* d_in, const int* in_sizes, int n_in,
                              void* d_out, int out_size, void* d_ws, size_t ws_size,
                              hipStream_t stream) {
    const float* x  = (const float*)d_in[0];
    const int*   ei = (const int*)d_in[1];     // [2, E] int32: row then col
    const float* W1 = (const float*)d_in[2];
    const float* b1 = (const float*)d_in[3];
    const float* W2 = (const float*)d_in[4];
    const float* b2 = (const float*)d_in[5];
    float* out = (float*)d_out;

    const int* row = ei;
    const int* col = ei + NE;

    // workspace layout
    unsigned* packed = (unsigned*)d_ws;                    // NB*STRIDE (~7.3 MB)
    unsigned* srow   = packed + (size_t)NB * STRIDE;       // NB*STRIDE (~7.3 MB)
    float2*   y2     = (float2*)(srow + (size_t)NB * STRIDE); // NN float2
    float*    z2     = (float*)(y2 + NN);                  // NN
    unsigned* rng32  = (unsigned*)(z2 + NN);               // NN
    unsigned* cursor = rng32 + NN;                         // NB

    hipMemsetAsync(cursor, 0, NB * sizeof(unsigned), stream);

    reorder_kernel  <<<NPB, RT, 0, stream>>>(row, col, cursor, packed);
    degscan_kernel  <<<NB, RT, 0, stream>>>(packed, cursor, (const float2*)x, y2, rng32);
    sortconv1_kernel<<<NB, RT, 0, stream>>>(packed, cursor, (const float2*)y2, rng32,
                                            W1, b1, W2, srow, z2);
    conv2_kernel    <<<(NN + 63) / 64, 256, 0, stream>>>(srow, rng32, z2, b2, out);
}

// Round 7
// 110.137 us; speedup vs baseline: 3.5607x; 1.0001x over previous
//
#include <hip/hip_runtime.h>
#include <math.h>

#define NN 100000
#define NE 1600000
#define BKT 391            // nodes per bucket (9-bit local index; 391*256 = 100096)
#define NB 256             // one bucket per CU
#define EPB 6400           // edges per reorder chunk; 250*6400 = 1,600,000 exact
#define NPB 250
#define CSUB 80            // slots per (bucket,chunk); Poisson(25), P(>80)~1e-17/cell
#define GPC (CSUB / 4)     // uint4 groups per chunk = 20
#define BSTRIDE (NPB * CSUB)   // 20000 words per bucket region in packed
#define SST 7168           // srow slots per bucket (mean 6250, sd ~79 -> +11.6 sigma)
#define RT 1024

// ---------- K1: reorder edges into deterministic (bucket,chunk) sub-slots ----------
// packed record = (row << 9) | cl, cl = col - bucket*BKT (< 391 < 512)
// NO global cursor: chunk c's records for bucket b live at packed[b*BSTRIDE + c*CSUB + r],
// count written unconditionally to cnt_bc[c*NB + b]  (=> no memset dispatch needed)
__global__ void __launch_bounds__(RT) reorder_kernel(
        const int* __restrict__ row, const int* __restrict__ col,
        unsigned* __restrict__ cnt_bc, unsigned* __restrict__ packed) {
    __shared__ int h[NB], lb[NB];
    __shared__ int wsum[RT / 64];
    __shared__ uint2 sga[EPB];                 // (record, final global slot) — 50 KB
    const int t = threadIdx.x;
    const int lane = t & 63, wid = t >> 6;
    const int c = blockIdx.x;
    const int e0 = c * EPB;

    for (int i = t; i < NB; i += RT) h[i] = 0;
    __syncthreads();

    // ---- load 2 int4 groups (1600 groups, 1024 threads) ----
    const int4* rv = (const int4*)(row + e0);
    const int4* cv = (const int4*)(col + e0);
    unsigned pk[8]; int bb[8];
#pragma unroll
    for (int u = 0; u < 8; ++u) bb[u] = -1;
#pragma unroll
    for (int g = 0; g < 2; ++g) {
        int grp = g * RT + t;
        if (grp < EPB / 4) {
            int4 r4 = rv[grp], c4 = cv[grp];
            int rr[4] = {r4.x, r4.y, r4.z, r4.w};
            int cc[4] = {c4.x, c4.y, c4.z, c4.w};
#pragma unroll
            for (int j = 0; j < 4; ++j) {
                int b = cc[j] / BKT;            // compiler magic-mul
                int cl = cc[j] - b * BKT;
                pk[4 * g + j] = ((unsigned)rr[j] << 9) | (unsigned)cl;
                bb[4 * g + j] = b;
            }
        }
    }
#pragma unroll
    for (int u = 0; u < 8; ++u)
        if (bb[u] >= 0) atomicAdd(&h[bb[u]], 1);
    __syncthreads();

    // ---- per-chunk counts out (unconditional: poison-safe, no zeroing) ----
    // ---- + exclusive scan over NB=256 bins for LDS compaction ----
    int v = (t < NB) ? h[t] : 0;
    if (t < NB) cnt_bc[(unsigned)c * NB + t] = (unsigned)v;
    int incl = v;
#pragma unroll
    for (int d = 1; d < 64; d <<= 1) {
        int u2 = __shfl_up(incl, d);
        if (lane >= d) incl += u2;
    }
    if (lane == 63) wsum[wid] = incl;
    __syncthreads();
    int off = 0;
#pragma unroll
    for (int j = 0; j < 3; ++j)
        if (j < wid) off += wsum[j];
    if (t < NB) lb[t] = off + incl - v;
    __syncthreads();
    for (int i = t; i < NB; i += RT) h[i] = 0;  // reuse as rank counters
    __syncthreads();

    // ---- rank-scatter into LDS with precomputed final address ----
#pragma unroll
    for (int u = 0; u < 8; ++u) {
        if (bb[u] >= 0) {
            int b = bb[u];
            int r = atomicAdd(&h[b], 1);
            unsigned a = (unsigned)b * BSTRIDE + (unsigned)c * CSUB + (unsigned)r;
            if (r >= CSUB) a = 0xFFFFFFFFu;     // overflow guard (P ~ 1e-17)
            sga[lb[b] + r] = make_uint2(pk[u], a);
        }
    }
    __syncthreads();
    // ---- write-out: run-coalesced scattered stores ----
    for (int i = t; i < EPB; i += RT) {
        uint2 e = sga[i];
        if (e.y != 0xFFFFFFFFu) packed[e.y] = e.x;
    }
}

// masked-stream macro body: iterate (chunk, uint4-group) space with validity counts
// caller provides PROCESS(word) applied to each valid record
#define MASKED_STREAM(PROCESS)                                              \
    for (int g = t; g < NPB * GPC; g += RT) {                               \
        int c_ = g / GPC;                                                   \
        int k_ = (g - c_ * GPC) * 4;                                        \
        int n_ = scnt[c_];                                                  \
        if (k_ < n_) {                                                      \
            uint4 p4 = *(const uint4*)(packed + base + c_ * CSUB + k_);     \
            PROCESS(p4.x);                                                  \
            if (k_ + 1 < n_) { PROCESS(p4.y); }                             \
            if (k_ + 2 < n_) { PROCESS(p4.z); }                             \
            if (k_ + 3 < n_) { PROCESS(p4.w); }                             \
        }                                                                   \
    }

// ---------- K2a: histogram + scan -> y2, rng32=(sex<<16|deg) ----------
__global__ void __launch_bounds__(RT) degscan_kernel(
        const unsigned* __restrict__ packed, const unsigned* __restrict__ cnt_bc,
        const float2* __restrict__ x2,
        float2* __restrict__ y2, unsigned* __restrict__ rng32) {
    __shared__ int cnt[BKT];
    __shared__ int scnt[NPB];
    __shared__ int wsum[(BKT + 63) / 64];      // 7
    const int t = threadIdx.x;
    const int lane = t & 63, wid = t >> 6;
    const int b = blockIdx.x;
    const unsigned base = (unsigned)b * BSTRIDE;

    for (int i = t; i < BKT; i += RT) cnt[i] = 0;
    if (t < NPB) scnt[t] = (int)cnt_bc[(unsigned)t * NB + b];
    __syncthreads();

#define HISTP(w) atomicAdd(&cnt[(w) & 511u], 1)
    MASKED_STREAM(HISTP)
#undef HISTP
    __syncthreads();

    // ---- exclusive scan over BKT bins (7 waves) ----
    int v = (t < BKT) ? cnt[t] : 0;
    int incl = v;
#pragma unroll
    for (int d = 1; d < 64; d <<= 1) {
        int u2 = __shfl_up(incl, d);
        if (lane >= d) incl += u2;
    }
    if (lane == 63 && wid < (BKT + 63) / 64) wsum[wid] = incl;
    __syncthreads();
    int off = 0;
#pragma unroll
    for (int j = 0; j < (BKT + 63) / 64 - 1; ++j)
        if (j < wid) off += wsum[j];
    if (t < BKT) {
        int sex = off + incl - v;              // compacted position, < ~7100 fits 16b
        int node = b * BKT + t;
        if (node < NN) {
            float dv = (v > 0) ? rsqrtf((float)v) : 0.0f;
            float2 xv = x2[node];
            y2[node] = make_float2(xv.x * dv, xv.y * dv);
            rng32[node] = ((unsigned)sex << 16) | (unsigned)v;
        }
    }
}

// ---------- K2b: rank-scatter (scan reused via rng32) + srow + fused conv1 ----------
__global__ void __launch_bounds__(RT) sortconv1_kernel(
        const unsigned* __restrict__ packed, const unsigned* __restrict__ cnt_bc,
        const float2* __restrict__ y2, const unsigned* __restrict__ rng32,
        const float* __restrict__ W1, const float* __restrict__ b1,
        const float* __restrict__ W2,
        unsigned* __restrict__ srow, float* __restrict__ z2) {
    __shared__ int rk[BKT], sexA[BKT], cntA[BKT];
    __shared__ int scnt[NPB];
    __shared__ int LtotS;
    __shared__ float sW0[64], sW1[64], sb1[64], sW2[64];
    __shared__ unsigned srt[SST];              // 28 KB
    const int t = threadIdx.x;
    const int b = blockIdx.x;
    const unsigned base = (unsigned)b * BSTRIDE;

    if (t < 64) { sW0[t] = W1[t]; sW1[t] = W1[64 + t]; sb1[t] = b1[t]; sW2[t] = W2[t]; }
    if (t == 0) LtotS = 0;
    for (int i = t; i < BKT; i += RT) rk[i] = 0;
    if (t < NPB) scnt[t] = (int)cnt_bc[(unsigned)t * NB + b];
    if (t < BKT) {
        int node = b * BKT + t;
        unsigned u = (node < NN) ? rng32[node] : 0u;
        sexA[t] = (int)(u >> 16);
        cntA[t] = (int)(u & 0xFFFFu);
    }
    __syncthreads();
    if (t < NPB) atomicAdd(&LtotS, scnt[t]);

    // ---- rank-scatter masked stream into srt (compacted sorted order) ----
#define SCATP(w) { int cl_ = (w) & 511u; int r_ = atomicAdd(&rk[cl_], 1); \
                   srt[sexA[cl_] + r_] = (w) >> 9; }
    MASKED_STREAM(SCATP)
#undef SCATP
    __syncthreads();

    // ---- coalesced srow write-out — conv2 consumes this ----
    const int Ltot = LtotS;
    const int L4 = Ltot >> 2;
    uint4* so4 = (uint4*)(srow + (unsigned)b * SST);
    for (int g = t; g < L4; g += RT) so4[g] = ((const uint4*)srt)[g];
    for (int i = 4 * L4 + t; i < Ltot; i += RT) srow[(unsigned)b * SST + i] = srt[i];

    // ---- fused conv1: 2 threads per node from resident srt (verified R5/R6) ----
    const int tau = t >> 1, par = t & 1;
    if (t < 2 * BKT) {
        int start = sexA[tau], deg = cntA[tau];
        float sx = 0.f, sy = 0.f;
        for (int k = start + par; k < start + deg; k += 2) {
            float2 w = y2[srt[k]];
            sx += w.x; sy += w.y;
        }
        sx += __shfl_xor(sx, 1); sy += __shfl_xor(sy, 1);
        float dv = (deg > 0) ? rsqrtf((float)deg) : 0.0f;
        float a0 = sx * dv, a1 = sy * dv;
        float acc = 0.0f;
        int j0 = par * 32;                     // MLP split across the pair
#pragma unroll
        for (int jj = 0; jj < 32; ++jj) {
            int j = j0 + jj;
            float h = fmaf(a0, sW0[j], fmaf(a1, sW1[j], sb1[j]));
            acc = fmaf(fmaxf(h, 0.0f), sW2[j], acc);
        }
        acc += __shfl_xor(acc, 1);
        int node = b * BKT + tau;
        if (par == 0 && node < NN) z2[node] = acc * dv;  // dis[row] pre-folded
    }
}

// ---------- K4: conv2 — 4-lane quad per node, rng32-driven CSR gather (verified R6) ----------
__global__ void conv2_kernel(const unsigned* __restrict__ srow, const unsigned* __restrict__ rng32,
                             const float* __restrict__ z2,
                             const float* __restrict__ b2, float* __restrict__ out) {
    int t = threadIdx.x;
    int lane = t & 3;
    int node = blockIdx.x * 64 + (t >> 2);
    if (node >= NN) return;
    unsigned u = rng32[node];
    int bk = node / BKT;                       // compiler magic-mul
    unsigned start = (unsigned)bk * SST + (u >> 16);
    int deg = (int)(u & 0xFFFFu);
    float s = 0.f;
    for (unsigned k = start + lane; k < start + (unsigned)deg; k += 4)
        s += z2[srow[k]];
    s += __shfl_xor(s, 1);
    s += __shfl_xor(s, 2);
    if (lane == 0) {
        float dv = (deg > 0) ? rsqrtf((float)deg) : 0.0f;
        out[node] = fmaxf(fmaf(dv, s, b2[0]), 0.0f);
    }
}

// ---------- launch: 4 dispatches, no memset ----------
extern "C" void kernel_launch(void* const* d_in, const int* in_sizes, int n_in,
                              void* d_out, int out_size, void* d_ws, size_t ws_size,
                              hipStream_t stream) {
    const float* x  = (const float*)d_in[0];
    const int*   ei = (const int*)d_in[1];     // [2, E] int32: row then col
    const float* W1 = (const float*)d_in[2];
    const float* b1 = (const float*)d_in[3];
    const float* W2 = (const float*)d_in[4];
    const float* b2 = (const float*)d_in[5];
    float* out = (float*)d_out;

    const int* row = ei;
    const int* col = ei + NE;

    // workspace layout
    unsigned* packed = (unsigned*)d_ws;                      // NB*BSTRIDE (~20.5 MB)
    unsigned* cnt_bc = packed + (size_t)NB * BSTRIDE;        // NPB*NB (256 KB)
    unsigned* srow   = cnt_bc + (size_t)NPB * NB;            // NB*SST (~7.3 MB)
    float2*   y2     = (float2*)(srow + (size_t)NB * SST);   // NN float2
    float*    z2     = (float*)(y2 + NN);                    // NN
    unsigned* rng32  = (unsigned*)(z2 + NN);                 // NN

    reorder_kernel  <<<NPB, RT, 0, stream>>>(row, col, cnt_bc, packed);
    degscan_kernel  <<<NB, RT, 0, stream>>>(packed, cnt_bc, (const float2*)x, y2, rng32);
    sortconv1_kernel<<<NB, RT, 0, stream>>>(packed, cnt_bc, (const float2*)y2, rng32,
                                            W1, b1, W2, srow, z2);
    conv2_kernel    <<<(NN + 63) / 64, 256, 0, stream>>>(srow, rng32, z2, b2, out);
}